// Round 10
// baseline (175.767 us; speedup 1.0000x reference)
//
#include <hip/hip_runtime.h>
#include <hip/hip_bf16.h>

// Problem constants: B=8, S=2048, E=768, HEAD=128
#define BB 8
#define SS 2048
#define EE 768
#define HH 128
#define MM (BB*SS)     // 16384
#define NQT 32         // 64-row q-tiles per batch
#define NCH 144        // chunks per batch: sum_{qt} ceil((qt+1)/4)

typedef __attribute__((ext_vector_type(8))) short bf16x8;
typedef __attribute__((ext_vector_type(8))) unsigned short ushort8;
typedef __attribute__((ext_vector_type(4))) float f32x4;

__device__ __forceinline__ unsigned short f2bf(float x) {
    unsigned int u = __float_as_uint(x);
    u += 0x7fff + ((u >> 16) & 1);   // RNE
    return (unsigned short)(u >> 16);
}
__device__ __forceinline__ float bf2f(unsigned short h) {
    return __uint_as_float(((unsigned int)h) << 16);
}
// async global->LDS, 16B per lane; LDS dest = wave-uniform base + lane*16
__device__ __forceinline__ void gld16(const unsigned short* g, unsigned short* l) {
    __builtin_amdgcn_global_load_lds(
        (const __attribute__((address_space(1))) unsigned int*)g,
        (__attribute__((address_space(3))) unsigned int*)l, 16, 0, 0);
}

// ---------------------------------------------------------------------------
// wcvt: Wb = bf16([Wq;Wk;Wv]) [384][768]. grid 288, ~2 us.
// ---------------------------------------------------------------------------
__global__ __launch_bounds__(256)
void wcvt(const float* __restrict__ Wq, const float* __restrict__ Wk,
          const float* __restrict__ Wv, unsigned short* __restrict__ Wb) {
    int i4 = (blockIdx.x * 256 + threadIdx.x) * 4;        // < 294912
    const float* src; int off;
    if (i4 < 98304)       { src = Wq; off = i4; }
    else if (i4 < 196608) { src = Wk; off = i4 - 98304; }
    else                  { src = Wv; off = i4 - 196608; }
    float4 v = *(const float4*)(src + off);
    ushort4 o;
    o.x = f2bf(v.x); o.y = f2bf(v.y); o.z = f2bf(v.z); o.w = f2bf(v.w);
    *(ushort4*)(Wb + i4) = o;
}

// ---------------------------------------------------------------------------
// Fused QKV GEMM v4: BK=64 -> 12 barrier-iterations (was 24) at constant
// total bytes. Tests the "per-iteration latency quantum" theory (R7/R8/R9:
// ~2us/iter invariant across byte counts and residency).
// grid (2 = n-half, 256 = m-tile): 64 rows x 192 cols per block.
// dbuf 2 x (A 8KB + B 24KB) = 64KB -> 2 blocks/CU. k-rotation kept.
// ---------------------------------------------------------------------------
__global__ __launch_bounds__(256, 2)
void qkv_fused(const float* __restrict__ X, const float* __restrict__ mask,
               const unsigned short* __restrict__ Wb,
               unsigned short* __restrict__ Q, unsigned short* __restrict__ K,
               unsigned short* __restrict__ Vt)
{
    const int nh = blockIdx.x;               // n-half: cols [nh*192, nh*192+192)
    const int m0 = blockIdx.y * 64;
    const int n0g = nh * 192;                // row offset into Wb [384][768]
    int kstart = blockIdx.y + nh * 6;
    kstart -= (kstart / 12) * 12;            // % 12

    // per-buf: A 4096 shorts | B 12288 shorts; two bufs = 32768 shorts (64KB)
    __shared__ __align__(16) unsigned short SM[32768];

    const int t = threadIdx.x, lane = t & 63;
    const int quad = lane >> 4, l16 = lane & 15;
    const int wave = t >> 6;
    const int wub = (t & 192) * 8;           // wave-uniform base (shorts)

    // A-staging: thread -> (row = t>>2, 16-col segment = t&3)
    const int arow = t >> 2, aseg = t & 3;
    const int ac0 = (2 * aseg) ^ (arow & 7);      // swizzled chunk slots
    const int ac1 = (2 * aseg + 1) ^ (arow & 7);
    const float* xrow = X + (size_t)(m0 + arow) * EE;
    const float amk = mask[m0 + arow];

    f32x4 acc[4][3];
#pragma unroll
    for (int i = 0; i < 4; i++)
#pragma unroll
        for (int ct = 0; ct < 3; ct++) acc[i][ct] = (f32x4)0.0f;

    // ---- prologue: stage k-slice kstart (64 wide) into buf 0 ----
    {
        const int kc = kstart * 64;
        unsigned short* Bd = SM + 4096;
#pragma unroll
        for (int i = 0; i < 6; i++) {        // B: 192 rows x 8 chunks
            int cg = i * 256 + t;
            int row = cg >> 3;
            int cc = (cg & 7) ^ (row & 7);
            gld16(Wb + (size_t)(n0g + row) * EE + kc + cc * 8, Bd + i * 2048 + wub);
        }
        float4 x0 = *(const float4*)(xrow + kc + aseg * 16);
        float4 x1 = *(const float4*)(xrow + kc + aseg * 16 + 4);
        float4 x2 = *(const float4*)(xrow + kc + aseg * 16 + 8);
        float4 x3 = *(const float4*)(xrow + kc + aseg * 16 + 12);
        ushort8 u0, u1;
        u0[0] = f2bf(x0.x * amk); u0[1] = f2bf(x0.y * amk);
        u0[2] = f2bf(x0.z * amk); u0[3] = f2bf(x0.w * amk);
        u0[4] = f2bf(x1.x * amk); u0[5] = f2bf(x1.y * amk);
        u0[6] = f2bf(x1.z * amk); u0[7] = f2bf(x1.w * amk);
        u1[0] = f2bf(x2.x * amk); u1[1] = f2bf(x2.y * amk);
        u1[2] = f2bf(x2.z * amk); u1[3] = f2bf(x2.w * amk);
        u1[4] = f2bf(x3.x * amk); u1[5] = f2bf(x3.y * amk);
        u1[6] = f2bf(x3.z * amk); u1[7] = f2bf(x3.w * amk);
        *(ushort8*)&SM[arow * 64 + ac0 * 8] = u0;
        *(ushort8*)&SM[arow * 64 + ac1 * 8] = u1;
    }

    for (int v = 0; v < 12; v++) {
        const int cur = v & 1, nxt = cur ^ 1;
        __syncthreads();   // staging of `cur` (gld16 vmcnt + ds_writes) complete

        float4 x0, x1, x2, x3;
        const bool more = (v + 1 < 12);
        if (more) {
            int kn = kstart + v + 1;
            if (kn >= 12) kn -= 12;
            const int knc = kn * 64;
            unsigned short* Bd = SM + nxt * 16384 + 4096;
#pragma unroll
            for (int i = 0; i < 6; i++) {
                int cg = i * 256 + t;
                int row = cg >> 3;
                int cc = (cg & 7) ^ (row & 7);
                gld16(Wb + (size_t)(n0g + row) * EE + knc + cc * 8, Bd + i * 2048 + wub);
            }
            x0 = *(const float4*)(xrow + knc + aseg * 16);
            x1 = *(const float4*)(xrow + knc + aseg * 16 + 4);
            x2 = *(const float4*)(xrow + knc + aseg * 16 + 8);
            x3 = *(const float4*)(xrow + knc + aseg * 16 + 12);
        }

        // compute on current buffer (BK=64: kk=0,1, 24 MFMA/wave)
        {
            const unsigned short* Ab = SM + cur * 16384;
            const unsigned short* Bb = Ab + 4096;
#pragma unroll
            for (int kk = 0; kk < 2; kk++) {
                bf16x8 a[4], bfr[3];
#pragma unroll
                for (int i = 0; i < 4; i++) {
                    int row = i * 16 + l16;
                    a[i] = *(const bf16x8*)&Ab[row * 64 + (((kk * 4 + quad) ^ (l16 & 7)) << 3)];
                }
#pragma unroll
                for (int ct = 0; ct < 3; ct++) {
                    int row = wave * 48 + ct * 16 + l16;
                    bfr[ct] = *(const bf16x8*)&Bb[row * 64 + (((kk * 4 + quad) ^ (l16 & 7)) << 3)];
                }
#pragma unroll
                for (int i = 0; i < 4; i++)
#pragma unroll
                    for (int ct = 0; ct < 3; ct++)
                        acc[i][ct] = __builtin_amdgcn_mfma_f32_16x16x32_bf16(a[i], bfr[ct], acc[i][ct], 0, 0, 0);
            }
        }

        if (more) {   // convert + ds_write next A
            ushort8 u0, u1;
            u0[0] = f2bf(x0.x * amk); u0[1] = f2bf(x0.y * amk);
            u0[2] = f2bf(x0.z * amk); u0[3] = f2bf(x0.w * amk);
            u0[4] = f2bf(x1.x * amk); u0[5] = f2bf(x1.y * amk);
            u0[6] = f2bf(x1.z * amk); u0[7] = f2bf(x1.w * amk);
            u1[0] = f2bf(x2.x * amk); u1[1] = f2bf(x2.y * amk);
            u1[2] = f2bf(x2.z * amk); u1[3] = f2bf(x2.w * amk);
            u1[4] = f2bf(x3.x * amk); u1[5] = f2bf(x3.y * amk);
            u1[6] = f2bf(x3.z * amk); u1[7] = f2bf(x3.w * amk);
            *(ushort8*)&SM[nxt * 16384 + arow * 64 + ac0 * 8] = u0;
            *(ushort8*)&SM[nxt * 16384 + arow * 64 + ac1 * 8] = u1;
        }
    }

    // ---- epilogue: route n -> Q / K (direct); V via LDS-bounce transpose ----
#pragma unroll
    for (int i = 0; i < 4; i++)
#pragma unroll
        for (int r = 0; r < 4; r++) {
            int m = m0 + i * 16 + quad * 4 + r;
#pragma unroll
            for (int ct = 0; ct < 3; ct++) {
                int n = n0g + wave * 48 + ct * 16 + l16;
                if (n < 128)      Q[(size_t)m * HH + n] = f2bf(acc[i][ct][r]);
                else if (n < 256) K[(size_t)m * HH + (n - 128)] = f2bf(acc[i][ct][r]);
            }
        }
    if (nh == 1) {
        __syncthreads();
#pragma unroll
        for (int i = 0; i < 4; i++)
#pragma unroll
            for (int r = 0; r < 4; r++) {
                int tok = i * 16 + quad * 4 + r;
                int ccw = tok >> 3, wd = tok & 7;
#pragma unroll
                for (int ct = 0; ct < 3; ct++) {
                    int n = n0g + wave * 48 + ct * 16 + l16;
                    if (n >= 256) {
                        int h = n - 256;
                        SM[h * 64 + ((ccw ^ (h & 7)) << 3) + wd] = f2bf(acc[i][ct][r]);
                    }
                }
            }
        __syncthreads();
        const int bidx = m0 >> 11, mloc = m0 & 2047;
#pragma unroll
        for (int i = 0; i < 4; i++) {
            int cg = i * 256 + t;
            int h = cg >> 3, cc = cg & 7;
            ulonglong2 v2 = *(const ulonglong2*)&SM[h * 64 + ((cc ^ (h & 7)) << 3)];
            *(ulonglong2*)&Vt[((size_t)bidx * HH + h) * SS + mloc + cc * 8] = v2;
        }
    }
}

// ---------------------------------------------------------------------------
// Flash attention v2: 128-token K-step -> ceil(n64/2) barrier-iterations
// (was n64) at constant bytes. Ks/Vs [128][132] (stride 132: ~2-way banks),
// Ps wave-private reused across the two 64-token PV halves (no extra barrier;
// same-wave LDS ops are ordered). LDS 76.8KB -> 2 blocks/CU.
// grid (144, 8), block 256 (4 waves x 16 q-rows).
// ---------------------------------------------------------------------------
__global__ __launch_bounds__(256, 2)
void attn(const unsigned short* __restrict__ Q, const unsigned short* __restrict__ K,
          const unsigned short* __restrict__ Vt,
          unsigned short* __restrict__ Po, float* __restrict__ Pm, float* __restrict__ Pl)
{
    const int c = blockIdx.x, b = blockIdx.y;
    int g = (int)((__builtin_sqrtf(2.0f * c + 1.0f) - 1.0f) * 0.5f);
    while (2 * (g + 1) * (g + 2) <= c) g++;
    while (2 * g * (g + 1) > c) g--;
    const int idx = c - 2 * g * (g + 1);
    const int qt = 4 * g + idx / (g + 1);
    const int ch = idx % (g + 1);
    const int q0 = qt * 64;
    const int kt0 = ch * 4;
    const int kt1 = min(kt0 + 4, qt + 1);
    const int nbig = (kt1 - kt0 + 1) >> 1;

    const int t = threadIdx.x, lane = t & 63;
    const int wave = t >> 6, quad = lane >> 4, l16 = lane & 15;

    __shared__ __align__(16) unsigned short Ks[128 * 132];   // [tok][d]
    __shared__ __align__(16) unsigned short Vs[128 * 132];   // [h][tok]
    __shared__ __align__(16) unsigned short Ps[4][16 * 72];  // per-wave [row][tok64]

    bf16x8 qf[4];
    {
        const unsigned short* qrow = Q + (size_t)(b * SS + q0 + wave * 16 + l16) * HH;
#pragma unroll
        for (int dd = 0; dd < 4; dd++)
            qf[dd] = *(const bf16x8*)(qrow + dd * 32 + quad * 8);
    }

    f32x4 o[8];
#pragma unroll
    for (int j = 0; j < 8; j++) o[j] = (f32x4)0.0f;
    f32x4 o9 = (f32x4)0.0f;
    float mrow[4];
#pragma unroll
    for (int r = 0; r < 4; r++) mrow[r] = -1e30f;

    const float sscale = 0.08838834764831845f * 1.4426950408889634f;

    bf16x8 ones;
    {
        short e = (l16 == 0) ? (short)0x3F80 : (short)0;
        ones = (bf16x8){e, e, e, e, e, e, e, e};
    }

    for (int ib = 0; ib < nbig; ib++) {
        const int ktA = kt0 + 2 * ib;
        const bool bvalid = (ktA + 1 < kt1);
        const int ktB = bvalid ? ktA + 1 : ktA;   // dup tile A when no B (masked)
        const int k0a = ktA * 64, k0b = ktB * 64;

        __syncthreads();
        // stage K: 128 tokens x 128 d
#pragma unroll
        for (int it = 0; it < 8; it++) {
            int flat = it * 256 + t;
            int row = flat >> 4, c8 = (flat & 15) * 8;
            int tok = (row < 64) ? (k0a + row) : (k0b + row - 64);
            *(ulonglong2*)&Ks[row * 132 + c8] =
                *(const ulonglong2*)(K + (size_t)(b * SS + tok) * HH + c8);
        }
        // stage V^T: 128 h x 128 tokens
#pragma unroll
        for (int it = 0; it < 8; it++) {
            int flat = it * 256 + t;
            int h = flat >> 4, c8 = (flat & 15) * 8;
            int tok = (c8 < 64) ? (k0a + c8) : (k0b + c8 - 64);
            *(ulonglong2*)&Vs[h * 132 + c8] =
                *(const ulonglong2*)(Vt + ((size_t)b * HH + h) * SS + tok);
        }
        __syncthreads();

        // S = Q K^T over 128 tokens (8 col-tiles)
        f32x4 s[8];
#pragma unroll
        for (int ct = 0; ct < 8; ct++) s[ct] = (f32x4)0.0f;
#pragma unroll
        for (int dd = 0; dd < 4; dd++) {
#pragma unroll
            for (int ct = 0; ct < 8; ct++) {
                bf16x8 kfr = *(const bf16x8*)&Ks[(ct * 16 + l16) * 132 + dd * 32 + quad * 8];
                s[ct] = __builtin_amdgcn_mfma_f32_16x16x32_bf16(qf[dd], kfr, s[ct], 0, 0, 0);
            }
        }

        const bool diagA = (ktA == qt), diagB = (ktB == qt);
        float sv[8][4];
#pragma unroll
        for (int ct = 0; ct < 8; ct++) {
            int col = ((ct < 4) ? (k0a + ct * 16) : (k0b + (ct - 4) * 16)) + l16;
            bool dg = (ct < 4) ? diagA : diagB;
            bool forceB = (ct >= 4) && !bvalid;
#pragma unroll
            for (int r = 0; r < 4; r++) {
                float vv = s[ct][r] * sscale;
                int row = q0 + wave * 16 + quad * 4 + r;
                sv[ct][r] = (forceB || (dg && col > row)) ? -1e30f : vv;
            }
        }

        // online softmax over 128 tokens
        float alpha[4];
#pragma unroll
        for (int r = 0; r < 4; r++) {
            float v = sv[0][r];
#pragma unroll
            for (int ct = 1; ct < 8; ct++) v = fmaxf(v, sv[ct][r]);
            v = fmaxf(v, __shfl_xor(v, 1));
            v = fmaxf(v, __shfl_xor(v, 2));
            v = fmaxf(v, __shfl_xor(v, 4));
            v = fmaxf(v, __shfl_xor(v, 8));
            float mnew = fmaxf(mrow[r], v);
            alpha[r] = exp2f(mrow[r] - mnew);
            mrow[r]  = mnew;
        }
        // rescale accumulators once per big-iter
#pragma unroll
        for (int j = 0; j < 8; j++)
#pragma unroll
            for (int r = 0; r < 4; r++) o[j][r] *= alpha[r];
#pragma unroll
        for (int r = 0; r < 4; r++) o9[r] *= alpha[r];

        // ---- half 1: tokens 0..63 ----
#pragma unroll
        for (int ct = 0; ct < 4; ct++)
#pragma unroll
            for (int r = 0; r < 4; r++) {
                float p = exp2f(sv[ct][r] - mrow[r]);
                Ps[wave][(quad * 4 + r) * 72 + ct * 16 + l16] = f2bf(p);
            }
#pragma unroll
        for (int kk = 0; kk < 2; kk++) {
            bf16x8 pf = *(const bf16x8*)&Ps[wave][l16 * 72 + kk * 32 + quad * 8];
#pragma unroll
            for (int j = 0; j < 8; j++) {
                bf16x8 vf = *(const bf16x8*)&Vs[(j * 16 + l16) * 132 + kk * 32 + quad * 8];
                o[j] = __builtin_amdgcn_mfma_f32_16x16x32_bf16(pf, vf, o[j], 0, 0, 0);
            }
            o9 = __builtin_amdgcn_mfma_f32_16x16x32_bf16(pf, ones, o9, 0, 0, 0);
        }
        // ---- half 2: tokens 64..127 (Ps reused; same-wave LDS ordering) ----
#pragma unroll
        for (int ct = 4; ct < 8; ct++)
#pragma unroll
            for (int r = 0; r < 4; r++) {
                float p = exp2f(sv[ct][r] - mrow[r]);
                Ps[wave][(quad * 4 + r) * 72 + (ct - 4) * 16 + l16] = f2bf(p);
            }
#pragma unroll
        for (int kk = 0; kk < 2; kk++) {
            bf16x8 pf = *(const bf16x8*)&Ps[wave][l16 * 72 + kk * 32 + quad * 8];
#pragma unroll
            for (int j = 0; j < 8; j++) {
                bf16x8 vf = *(const bf16x8*)&Vs[(j * 16 + l16) * 132 + 64 + kk * 32 + quad * 8];
                o[j] = __builtin_amdgcn_mfma_f32_16x16x32_bf16(pf, vf, o[j], 0, 0, 0);
            }
            o9 = __builtin_amdgcn_mfma_f32_16x16x32_bf16(pf, ones, o9, 0, 0, 0);
        }
    }

    // store partials: Po permuted layout [row][l16][j] -> 16B/lane stores
    const size_t pidx = (size_t)b * NCH + c;
    const size_t pobase = pidx * (64 * 128);
    const size_t mbase  = pidx * 64;
#pragma unroll
    for (int r = 0; r < 4; r++) {
        int row = wave * 16 + quad * 4 + r;
        if (l16 == 0) { Pm[mbase + row] = mrow[r]; Pl[mbase + row] = o9[r]; }
        ushort8 val;
#pragma unroll
        for (int j = 0; j < 8; j++) val[j] = f2bf(o[j][r]);
        *(ushort8*)&Po[pobase + (size_t)row * 128 + l16 * 8] = val;
    }
}

// ---------------------------------------------------------------------------
// Combine — UNCHANGED. grid (32, 8, 4), 16 q-rows per block.
// ---------------------------------------------------------------------------
__global__ __launch_bounds__(256)
void combine(const unsigned short* __restrict__ Po, const float* __restrict__ Pm,
             const float* __restrict__ Pl, float* __restrict__ Out)
{
    const int qt = blockIdx.x, b = blockIdx.y, qr = blockIdx.z;
    const int g = qt >> 2;
    const int n_ch = g + 1;
    const int cbase = 2 * g * (g + 1) + (qt - 4 * g) * (g + 1);
    const size_t p0 = (size_t)b * NCH + cbase;
    const int t = threadIdx.x;
    const int p = t & 127;
    const int col = (p & 7) * 16 + (p >> 3);
    const int rh = t >> 7;

    __shared__ float sm[8][16], sl[8][16], sw[8][16];
    __shared__ float sinv[16];

    if (t < 128) {
        int s = t >> 4, row = t & 15;
        float mv = -1e30f, lv = 0.0f;
        if (s < n_ch) {
            mv = Pm[(p0 + s) * 64 + qr * 16 + row];
            lv = Pl[(p0 + s) * 64 + qr * 16 + row];
        }
        sm[s][row] = mv; sl[s][row] = lv;
    }
    __syncthreads();
    if (t < 16) {
        int row = t;
        float ms = sm[0][row];
#pragma unroll
        for (int s = 1; s < 8; s++) ms = fmaxf(ms, sm[s][row]);
        float l = 0.0f;
#pragma unroll
        for (int s = 0; s < 8; s++) {
            float w = (sm[s][row] > -1e29f) ? exp2f(sm[s][row] - ms) : 0.0f;
            sw[s][row] = w;
            l += w * sl[s][row];
        }
        sinv[row] = 1.0f / l;
    }
    __syncthreads();

#pragma unroll
    for (int pass = 0; pass < 8; pass++) {
        int row = pass * 2 + rh;
        int grow = qr * 16 + row;
        float acc = 0.0f;
#pragma unroll
        for (int s = 0; s < 8; s++) {
            int ss = (s < n_ch) ? s : 0;
            acc += sw[s][row] * bf2f(Po[(p0 + ss) * 8192 + (size_t)grow * 128 + p]);
        }
        Out[((size_t)b * SS + qt * 64 + grow) * HH + col] = acc * sinv[row];
    }
}

extern "C" void kernel_launch(void* const* d_in, const int* in_sizes, int n_in,
                              void* d_out, int out_size, void* d_ws, size_t ws_size,
                              hipStream_t stream) {
    const float* X    = (const float*)d_in[0];
    const float* mask = (const float*)d_in[1];
    const float* Wq   = (const float*)d_in[2];
    const float* Wk   = (const float*)d_in[3];
    const float* Wv   = (const float*)d_in[4];

    char* ws = (char*)d_ws;
    unsigned short* Wb = (unsigned short*)ws; ws += (size_t)384 * EE * 2;      // 0.59 MB
    unsigned short* Q  = (unsigned short*)ws; ws += (size_t)MM * HH * 2;       // 4 MB
    unsigned short* Kb = (unsigned short*)ws; ws += (size_t)MM * HH * 2;       // 4 MB
    unsigned short* Vt = (unsigned short*)ws; ws += (size_t)MM * HH * 2;       // 4 MB
    unsigned short* Po = (unsigned short*)ws; ws += (size_t)BB * NCH * 64 * 128 * 2; // 18.9 MB
    float* Pm = (float*)ws; ws += (size_t)BB * NCH * 64 * 4;
    float* Pl = (float*)ws;

    wcvt<<<288, 256, 0, stream>>>(Wq, Wk, Wv, Wb);
    qkv_fused<<<dim3(2, 256), 256, 0, stream>>>(X, mask, Wb, Q, Kb, Vt);
    attn<<<dim3(NCH, BB), 256, 0, stream>>>(Q, Kb, Vt, Po, Pm, Pl);
    combine<<<dim3(NQT, BB, 4), 256, 0, stream>>>(Po, Pm, Pl, (float*)d_out);
}